// Round 5
// baseline (109.937 us; speedup 1.0000x reference)
//
#include <hip/hip_runtime.h>
#include <stdint.h>

typedef __attribute__((ext_vector_type(4))) float f32x4;
typedef __attribute__((ext_vector_type(4))) unsigned int u32x4;
typedef __attribute__((ext_vector_type(2))) long long i64x2;
typedef long long i64_t;

#define NB 16
#define NC 128
#define NH 128
#define NW 128
#define HP 130
#define WP 130

// ---------------- prep: wfrag (B sign bytes), sf = mean|w|, theta (activation threshold) ----
// wfrag flat byte f = p*8192 + kb*2048 + nip*1024 + l*16 + nl*8 + j   (ni = nip*2+nl)
// o = ni*16 + (l&15), c = kb*32 + (l>>4)*8 + j
__global__ __launch_bounds__(256) void k_prep(const float* __restrict__ cw,
                                              const float* __restrict__ b1,
                                              const float* __restrict__ pa,
                                              const float* __restrict__ b2,
                                              float* __restrict__ sf,
                                              float* __restrict__ theta,
                                              unsigned char* __restrict__ wf) {
    int b = blockIdx.x, t = threadIdx.x;    // 288 blocks
    int f = b * 256 + t;                    // < 73728
    int j   = f & 7;
    int nl  = (f >> 3) & 1;
    int l   = (f >> 4) & 63;
    int nip = (f >> 10) & 1;
    int kb  = (f >> 11) & 3;
    int p   = f >> 13;
    int o = (nip * 2 + nl) * 16 + (l & 15);
    int c = kb * 32 + (l >> 4) * 8 + j;
    float wv = cw[o * 1152 + c * 9 + p];
    wf[f] = wv > 0.f ? (unsigned char)0x38
                     : (wv < 0.f ? (unsigned char)0xB8 : (unsigned char)0x00);
    if (b < 64) {                           // sf[b] = mean|w| over 1152
        __shared__ float red[4];
        const float* pp = cw + b * 1152;
        float s = 0.f;
        for (int i = t; i < 1152; i += 256) s += fabsf(pp[i]);
#pragma unroll
        for (int off = 32; off > 0; off >>= 1) s += __shfl_down(s, off);
        if ((t & 63) == 0) red[t >> 6] = s;
        __syncthreads();
        if (t == 0) sf[b] = (red[0] + red[1] + red[2] + red[3]) * (1.0f / 1152.0f);
    }
    if (b == 64 && t < NC) {                // theta: sign(prelu(v+b1)+b2) == sign(v - theta)
        float B1 = b1[t], A = pa[t], B2 = b2[t];   // prelu slope a>0 -> monotone
        theta[t] = (-B2 >= 0.f) ? (-B1 - B2) : (-B1 - B2 / A);
    }
}

__device__ __forceinline__ unsigned int pk8(float v, float th) {
    return v > th ? 0x38u : (v < th ? 0xB8u : 0u);
}

// ---------------- fused: stage signs of 4 padded x-rows into LDS (pi+XOR layout),
//                  implicit-GEMM fp8 MFMA conv, epilogue writes conv*sf + shortcut ----------------
__global__ __launch_bounds__(256, 2) void k_fused(
    const float* __restrict__ x, const float* __restrict__ theta,
    const unsigned char* __restrict__ wf, const float* __restrict__ sf,
    const float* __restrict__ pw, float* __restrict__ out) {
    __shared__ __align__(16) unsigned char AT[66560];   // 4 padded rows x 130 wp x 128 B
    int bxr = blockIdx.x;
    int bx = (bxr & 7) * 128 + (bxr >> 3);  // XCD swizzle: adjacent h2b share an XCD L2
    int nb = bx >> 6;
    int h2b = bx & 63;
    int t = threadIdx.x;

    // ---- staging phase ----
    if (t < 64) {                           // pad columns wp=0,129: 64 zero units
        int rho = t >> 4, colside = (t >> 3) & 1, u = t & 7;
        int wp = colside * (WP - 1);
        u32x4 z = {0u, 0u, 0u, 0u};
        *(u32x4*)(AT + (size_t)(rho * WP + wp) * NC + ((u ^ (wp & 7)) << 4)) = z;
    }
    {
        int wp = (t & 127) + 1;             // this thread's column (w = wp-1)
        int uhalf = t >> 7;                 // units uhalf*4 .. +3
        const float* xcol = x + ((size_t)nb * NC) * (NH * NW) + (wp - 1);
        unsigned char* dstc = AT + (size_t)wp * NC;
#pragma unroll 1
        for (int uu = 0; uu < 4; ++uu) {
            int u = uhalf * 4 + uu;
            int lg = u >> 1, xb2 = u & 1;
            int c1 = 64 * xb2 + lg * 8;     // unit bytes 0..7  = channels c1..c1+7
            int c2 = c1 + 32;               // unit bytes 8..15 = channels c2..c2+7
            f32x4 t0 = *(const f32x4*)(theta + c1);
            f32x4 t1 = *(const f32x4*)(theta + c1 + 4);
            f32x4 t2 = *(const f32x4*)(theta + c2);
            f32x4 t3 = *(const f32x4*)(theta + c2 + 4);
            unsigned char* dst0 = dstc + ((u ^ (wp & 7)) << 4);
#pragma unroll
            for (int rho = 0; rho < 4; ++rho) {
                int h = 2 * h2b + rho - 1;
                u32x4 v = {0u, 0u, 0u, 0u};
                if (h >= 0 && h < NH) {     // block-uniform branch
                    const float* xp = xcol + (size_t)h * NW;
                    float a0 = xp[(size_t)(c1 + 0) * (NH * NW)];
                    float a1 = xp[(size_t)(c1 + 1) * (NH * NW)];
                    float a2 = xp[(size_t)(c1 + 2) * (NH * NW)];
                    float a3 = xp[(size_t)(c1 + 3) * (NH * NW)];
                    float a4 = xp[(size_t)(c1 + 4) * (NH * NW)];
                    float a5 = xp[(size_t)(c1 + 5) * (NH * NW)];
                    float a6 = xp[(size_t)(c1 + 6) * (NH * NW)];
                    float a7 = xp[(size_t)(c1 + 7) * (NH * NW)];
                    float b0 = xp[(size_t)(c2 + 0) * (NH * NW)];
                    float b1v = xp[(size_t)(c2 + 1) * (NH * NW)];
                    float b2v = xp[(size_t)(c2 + 2) * (NH * NW)];
                    float b3 = xp[(size_t)(c2 + 3) * (NH * NW)];
                    float b4 = xp[(size_t)(c2 + 4) * (NH * NW)];
                    float b5 = xp[(size_t)(c2 + 5) * (NH * NW)];
                    float b6 = xp[(size_t)(c2 + 6) * (NH * NW)];
                    float b7 = xp[(size_t)(c2 + 7) * (NH * NW)];
                    v.x = pk8(a0, t0.x) | (pk8(a1, t0.y) << 8) |
                          (pk8(a2, t0.z) << 16) | (pk8(a3, t0.w) << 24);
                    v.y = pk8(a4, t1.x) | (pk8(a5, t1.y) << 8) |
                          (pk8(a6, t1.z) << 16) | (pk8(a7, t1.w) << 24);
                    v.z = pk8(b0, t2.x) | (pk8(b1v, t2.y) << 8) |
                          (pk8(b2v, t2.z) << 16) | (pk8(b3, t2.w) << 24);
                    v.w = pk8(b4, t3.x) | (pk8(b5, t3.y) << 8) |
                          (pk8(b6, t3.z) << 16) | (pk8(b7, t3.w) << 24);
                }
                *(u32x4*)(dst0 + (size_t)rho * (WP * NC)) = v;   // conflict-free b128
            }
        }
    }

    int wid = t >> 6;
    int l = t & 63;
    int lr = l & 15, lg = l >> 4;
    int h = h2b * 2 + (wid >> 1);           // output row for this wave
    int w0 = (wid & 1) * 64;                // output col base
    f32x4 acc[4][4];
    f32x4 zero = {0.f, 0.f, 0.f, 0.f};
#pragma unroll
    for (int mi = 0; mi < 4; ++mi)
#pragma unroll
        for (int ni = 0; ni < 4; ++ni) acc[mi][ni] = zero;
    __syncthreads();

    // ---- MFMA phase (unchanged from validated k2) ----
#pragma unroll
    for (int p = 0; p < 9; ++p) {
        int kh = p / 3, kw = p % 3;         // constants after unroll
        int rho = (wid >> 1) + kh;          // local padded row 0..3
        int wp = w0 + kw + lr;
        int sb7 = wp & 7;
        const unsigned char* ap = AT + (size_t)(rho * WP + wp) * NC;
        const unsigned char* brow = wf + p * 8192 + l * 16;
        i64_t bfr[4][4];
#pragma unroll
        for (int kb = 0; kb < 4; ++kb) {    // B: 16B/lane coalesced, L2-hot
            i64x2 b01 = *(const i64x2*)(brow + kb * 2048);
            i64x2 b23 = *(const i64x2*)(brow + kb * 2048 + 1024);
            bfr[kb][0] = b01.x; bfr[kb][1] = b01.y;
            bfr[kb][2] = b23.x; bfr[kb][3] = b23.y;
        }
        int off0 = ((lg * 2) ^ sb7) << 4;   // logical 16B-unit -> physical (XOR swizzle)
        int off1 = ((lg * 2 + 1) ^ sb7) << 4;
#pragma unroll
        for (int mi = 0; mi < 4; ++mi) {    // 2 x ds_read_b128 = all 4 kb fragments
            i64x2 a01 = *(const i64x2*)(ap + mi * 2048 + off0);
            i64x2 a23 = *(const i64x2*)(ap + mi * 2048 + off1);
            i64_t af[4] = {a01.x, a01.y, a23.x, a23.y};
#pragma unroll
            for (int kb = 0; kb < 4; ++kb)
#pragma unroll
                for (int ni = 0; ni < 4; ++ni)
                    acc[mi][ni] = __builtin_amdgcn_mfma_f32_16x16x32_fp8_fp8(
                        af[kb], bfr[kb][ni], acc[mi][ni], 0, 0, 0);
        }
    }
    __syncthreads();                        // A-tile dead; reuse LDS for epilogue transpose

    // ---- epilogue: conv*sf + fused shortcut, single write of out ----
    float (*Tt)[33] = (float (*)[33])(AT + wid * 8448);
    int s1 = h & 1, h2 = h >> 1;
    float* ob = out + (((size_t)nb * 256 + s1 * 2) * 64 + h2) * 64;
    const float* xrow = x + ((size_t)nb * NC) * (NH * NW) + (size_t)h * NW;
    int og = l >> 5;
    int wl_lo = l & 31;
#pragma unroll
    for (int half = 0; half < 2; ++half) {
#pragma unroll
        for (int mi2 = 0; mi2 < 2; ++mi2) {
            int mi = half * 2 + mi2;
#pragma unroll
            for (int ni = 0; ni < 4; ++ni)
#pragma unroll
                for (int r = 0; r < 4; ++r)
                    Tt[ni * 16 + lr][mi2 * 16 + lg * 4 + r] = acc[mi][ni][r];
        }
        asm volatile("" ::: "memory");      // per-wave DS in-order; pin compiler order
        int w = w0 + half * 32 + wl_lo;
        int lanoff = (w & 1) * 4096 + (w >> 1);
        for (int oo = 0; oo < 32; ++oo) {
            int o = 2 * oo + og;
            float xv0 = xrow[(size_t)(2 * o) * (NH * NW) + w];       // L2-hot (staged above)
            float xv1 = xrow[(size_t)(2 * o + 1) * (NH * NW) + w];
            ob[(size_t)o * 16384 + lanoff] =
                Tt[o][wl_lo] * sf[o] + pw[2 * o] * xv0 + pw[2 * o + 1] * xv1;
        }
        asm volatile("" ::: "memory");      // WAR: half 1 writes after half 0 reads
    }
}

extern "C" void kernel_launch(void* const* d_in, const int* in_sizes, int n_in,
                              void* d_out, int out_size, void* d_ws, size_t ws_size,
                              hipStream_t stream) {
    const float* x  = (const float*)d_in[0];
    const float* b1 = (const float*)d_in[1];
    const float* pa = (const float*)d_in[2];
    const float* b2 = (const float*)d_in[3];
    const float* cw = (const float*)d_in[4];
    const float* pw = (const float*)d_in[5];
    float* out = (float*)d_out;
    // ws layout: [0,256) sf | [256,768) theta (128 f32) | [768, 768+73728) wfrag fp8
    float* sf = (float*)d_ws;
    float* theta = (float*)((char*)d_ws + 256);
    unsigned char* wfr = (unsigned char*)d_ws + 768;

    k_prep<<<288, 256, 0, stream>>>(cw, b1, pa, b2, sf, theta, wfr);
    k_fused<<<1024, 256, 0, stream>>>(x, theta, wfr, sf, pw, out);
}

// Round 6
// 95.306 us; speedup vs baseline: 1.1535x; 1.1535x over previous
//
#include <hip/hip_runtime.h>
#include <stdint.h>

typedef __attribute__((ext_vector_type(4))) float f32x4;
typedef __attribute__((ext_vector_type(4))) unsigned int u32x4;
typedef __attribute__((ext_vector_type(2))) long long i64x2;
typedef long long i64_t;

#define NB 16
#define NC 128
#define NH 128
#define NW 128
#define HP 130
#define WP 130

typedef const __attribute__((address_space(1))) void gv_t;
typedef __attribute__((address_space(3))) void lv_t;
__device__ __forceinline__ void gload16(const void* g, void* l) {
    __builtin_amdgcn_global_load_lds((gv_t*)g, (lv_t*)l, 16, 0, 0);
}

// ---------------- prep: wfrag (B sign bytes), sf = mean|w|, theta (activation threshold) ----
// wfrag flat byte f = p*8192 + kb*2048 + nip*1024 + l*16 + nl*8 + j   (ni = nip*2+nl)
// o = ni*16 + (l&15), c = kb*32 + (l>>4)*8 + j
__global__ __launch_bounds__(256) void k_prep(const float* __restrict__ cw,
                                              const float* __restrict__ b1,
                                              const float* __restrict__ pa,
                                              const float* __restrict__ b2,
                                              float* __restrict__ sf,
                                              float* __restrict__ theta,
                                              unsigned char* __restrict__ wf) {
    int b = blockIdx.x, t = threadIdx.x;    // 288 blocks
    int f = b * 256 + t;                    // < 73728
    int j   = f & 7;
    int nl  = (f >> 3) & 1;
    int l   = (f >> 4) & 63;
    int nip = (f >> 10) & 1;
    int kb  = (f >> 11) & 3;
    int p   = f >> 13;
    int o = (nip * 2 + nl) * 16 + (l & 15);
    int c = kb * 32 + (l >> 4) * 8 + j;
    float wv = cw[o * 1152 + c * 9 + p];
    wf[f] = wv > 0.f ? (unsigned char)0x38
                     : (wv < 0.f ? (unsigned char)0xB8 : (unsigned char)0x00);
    if (b < 64) {                           // sf[b] = mean|w| over 1152
        __shared__ float red[4];
        const float* pp = cw + b * 1152;
        float s = 0.f;
        for (int i = t; i < 1152; i += 256) s += fabsf(pp[i]);
#pragma unroll
        for (int off = 32; off > 0; off >>= 1) s += __shfl_down(s, off);
        if ((t & 63) == 0) red[t >> 6] = s;
        __syncthreads();
        if (t == 0) sf[b] = (red[0] + red[1] + red[2] + red[3]) * (1.0f / 1152.0f);
    }
    if (b == 64 && t < NC) {                // theta: sign(prelu(v+b1)+b2) == sign(v - theta)
        float B1 = b1[t], A = pa[t], B2 = b2[t];   // prelu slope a>0 -> monotone
        theta[t] = (-B2 >= 0.f) ? (-B1 - B2) : (-B1 - B2 / A);
    }
}

__device__ __forceinline__ unsigned int pk8(float v, float th) {
    return v > th ? 0x38u : (v < th ? 0xB8u : 0u);
}

// ---------------- k1: activation signs -> SB (padded NHWC fp8, pi+XOR layout),
//                  shortcut -> out.  Explicit MLP: 32 x-loads hoisted per half-batch. ----------------
__global__ __launch_bounds__(256) void k1_signs_shortcut(
    const float* __restrict__ x, const float* __restrict__ theta,
    const float* __restrict__ pw, unsigned char* __restrict__ SB,
    float* __restrict__ out) {
    __shared__ unsigned short T[128][65];   // [w][o] ; packs fp8 of c=2o (lo byte), 2o+1 (hi)
    int bx = blockIdx.x;                    // 16*130
    int nb = bx / 130;
    int hp = bx % 130;
    unsigned char* sbrow = SB + ((size_t)nb * HP + hp) * WP * NC;
    int t = threadIdx.x;
    if (hp == 0 || hp == HP - 1) {          // zero pad rows (16640 B)
        u32x4 z = {0u, 0u, 0u, 0u};
        for (int i = t; i < WP * NC / 16; i += 256)
            ((u32x4*)sbrow)[i] = z;
        return;
    }
    int h = hp - 1;
    int wp2 = t & 63;                       // w pair index: w = 2*wp2, 2*wp2+1
    int oq = t >> 6;                        // 0..3
    const float* xb = x + ((size_t)nb * NC) * (NH * NW) + (size_t)h * NW + 2 * wp2;
    int s1 = h & 1, h2 = h >> 1;
    float* ob = out + (((size_t)nb * 256 + s1 * 2) * 64 + h2) * 64 + wp2;
#pragma unroll
    for (int half = 0; half < 2; ++half) {
        float2 X0[8], X1[8];
#pragma unroll
        for (int ii = 0; ii < 8; ++ii) {    // 32 independent loads in flight
            int o = oq * 16 + half * 8 + ii;
            X0[ii] = *(const float2*)(xb + (size_t)(2 * o) * (NH * NW));
            X1[ii] = *(const float2*)(xb + (size_t)(2 * o + 1) * (NH * NW));
        }
#pragma unroll
        for (int ii = 0; ii < 8; ++ii) {
            int o = oq * 16 + half * 8 + ii;
            float2 th = *(const float2*)(theta + 2 * o);
            float2 pv = *(const float2*)(pw + 2 * o);
            unsigned int lo0 = pk8(X0[ii].x, th.x), hi0 = pk8(X1[ii].x, th.y);
            unsigned int lo1 = pk8(X0[ii].y, th.x), hi1 = pk8(X1[ii].y, th.y);
            T[2 * wp2][o]     = (unsigned short)(lo0 | (hi0 << 8));
            T[2 * wp2 + 1][o] = (unsigned short)(lo1 | (hi1 << 8));
            ob[(size_t)o * 16384]        = pv.x * X0[ii].x + pv.y * X1[ii].x;  // s2=0
            ob[(size_t)o * 16384 + 4096] = pv.x * X0[ii].y + pv.y * X1[ii].y;  // s2=1
        }
    }
    __syncthreads();
    if (t < 32) {                           // zero pad cols wp=0 and wp=129 (zeros: swizzle-invariant)
        int k = t & 15, side = t >> 4;
        uint2 z = {0u, 0u};
        *(uint2*)(sbrow + (side ? (size_t)(WP - 1) * NC : (size_t)0) + k * 8) = z;
    }
#pragma unroll
    for (int pp = 0; pp < 8; ++pp) {        // adjacent writeback, permuted gather (validated r4)
        int wloc = pp * 16 + (t >> 4);
        int k = t & 15;                     // physical 8B-unit index
        int wp = wloc + 1;
        int ell = (((k >> 1) ^ (wp & 7)) << 1) | (k & 1);   // logical pi-unit at this slot
        int o0 = (ell & 3) * 16 + (ell >> 2) * 4;           // its 4 channel-pairs in T
        unsigned int t0 = T[wloc][o0 + 0];
        unsigned int t1 = T[wloc][o0 + 1];
        unsigned int t2 = T[wloc][o0 + 2];
        unsigned int t3 = T[wloc][o0 + 3];
        uint2 v;
        v.x = t0 | (t1 << 16);
        v.y = t2 | (t3 << 16);
        *(uint2*)(sbrow + (size_t)wp * NC + k * 8) = v;
    }
}

// ---------------- k2: implicit-GEMM binary conv; A-tile in LDS (one DMA), fp8 MFMA ----------------
__global__ __launch_bounds__(256, 2) void k2_conv(
    const unsigned char* __restrict__ SB, const unsigned char* __restrict__ wf,
    const float* __restrict__ sf, float* __restrict__ out) {
    __shared__ __align__(16) unsigned char AT[66560];   // 4 padded rows x 130 x 128B
    int bxr = blockIdx.x;
    int bx = (bxr & 7) * 128 + (bxr >> 3);  // XCD swizzle (1024 % 8 == 0, bijective)
    int nb = bx >> 6;
    int h2b = bx & 63;
    int t = threadIdx.x;
    int wid = t >> 6;
    int l = t & 63;
    int lr = l & 15, lg = l >> 4;
    // stage 66,560 B = 4160 x 16 B, linear (SB rows hp = 2*h2b .. 2*h2b+3 are contiguous)
    const unsigned char* gsrc = SB + ((size_t)nb * HP + 2 * h2b) * (WP * NC);
#pragma unroll
    for (int i = 0; i < 16; ++i)
        gload16(gsrc + ((size_t)(i * 256 + t)) * 16, AT + (i * 256 + wid * 64) * 16);
    if (wid == 0)
        gload16(gsrc + ((size_t)(4096 + l)) * 16, AT + 4096 * 16);

    int h = h2b * 2 + (wid >> 1);           // output row for this wave
    int w0 = (wid & 1) * 64;                // output col base
    f32x4 acc[4][4];
    f32x4 zero = {0.f, 0.f, 0.f, 0.f};
#pragma unroll
    for (int mi = 0; mi < 4; ++mi)
#pragma unroll
        for (int ni = 0; ni < 4; ++ni) acc[mi][ni] = zero;
    __syncthreads();

#pragma unroll
    for (int p = 0; p < 9; ++p) {
        int kh = p / 3, kw = p % 3;         // constants after unroll
        int rho = (wid >> 1) + kh;          // local padded row 0..3
        int wp = w0 + kw + lr;
        int sb7 = wp & 7;
        const unsigned char* ap = AT + (size_t)(rho * WP + wp) * NC;
        const unsigned char* brow = wf + p * 8192 + l * 16;
        i64_t bfr[4][4];
#pragma unroll
        for (int kb = 0; kb < 4; ++kb) {    // B: 16B/lane coalesced, L2-hot
            i64x2 b01 = *(const i64x2*)(brow + kb * 2048);
            i64x2 b23 = *(const i64x2*)(brow + kb * 2048 + 1024);
            bfr[kb][0] = b01.x; bfr[kb][1] = b01.y;
            bfr[kb][2] = b23.x; bfr[kb][3] = b23.y;
        }
        int off0 = ((lg * 2) ^ sb7) << 4;   // logical 16B-block -> physical (XOR swizzle)
        int off1 = ((lg * 2 + 1) ^ sb7) << 4;
#pragma unroll
        for (int mi = 0; mi < 4; ++mi) {    // 2 x ds_read_b128 = all 4 kb fragments
            i64x2 a01 = *(const i64x2*)(ap + mi * 2048 + off0);
            i64x2 a23 = *(const i64x2*)(ap + mi * 2048 + off1);
            i64_t af[4] = {a01.x, a01.y, a23.x, a23.y};
#pragma unroll
            for (int kb = 0; kb < 4; ++kb)
#pragma unroll
                for (int ni = 0; ni < 4; ++ni)
                    acc[mi][ni] = __builtin_amdgcn_mfma_f32_16x16x32_fp8_fp8(
                        af[kb], bfr[kb][ni], acc[mi][ni], 0, 0, 0);
        }
    }
    __syncthreads();                        // A-tile dead; reuse LDS for epilogue transpose
    float (*Tt)[33] = (float (*)[33])(AT + wid * 8448);
    int s1 = h & 1, h2 = h >> 1;
    float* ob = out + (((size_t)nb * 256 + s1 * 2) * 64 + h2) * 64;
    int og = l >> 5;
    int wl_lo = l & 31;
#pragma unroll
    for (int half = 0; half < 2; ++half) {
#pragma unroll
        for (int mi2 = 0; mi2 < 2; ++mi2) {
            int mi = half * 2 + mi2;
#pragma unroll
            for (int ni = 0; ni < 4; ++ni)
#pragma unroll
                for (int r = 0; r < 4; ++r)
                    Tt[ni * 16 + lr][mi2 * 16 + lg * 4 + r] = acc[mi][ni][r];
        }
        asm volatile("" ::: "memory");      // per-wave DS in-order; pin compiler order
        int w = w0 + half * 32 + wl_lo;
        int lanoff = (w & 1) * 4096 + (w >> 1);
        for (int oo = 0; oo < 32; ++oo) {
            int o = 2 * oo + og;
            ob[(size_t)o * 16384 + lanoff] += Tt[o][wl_lo] * sf[o];
        }
        asm volatile("" ::: "memory");      // WAR: half 1 writes after half 0 reads
    }
}

extern "C" void kernel_launch(void* const* d_in, const int* in_sizes, int n_in,
                              void* d_out, int out_size, void* d_ws, size_t ws_size,
                              hipStream_t stream) {
    const float* x  = (const float*)d_in[0];
    const float* b1 = (const float*)d_in[1];
    const float* pa = (const float*)d_in[2];
    const float* b2 = (const float*)d_in[3];
    const float* cw = (const float*)d_in[4];
    const float* pw = (const float*)d_in[5];
    float* out = (float*)d_out;
    // ws layout: [0,256) sf | [256,768) theta | [768, 768+73728) wfrag | then SB (~34.6 MB)
    float* sf = (float*)d_ws;
    float* theta = (float*)((char*)d_ws + 256);
    unsigned char* wfr = (unsigned char*)d_ws + 768;
    unsigned char* SB  = (unsigned char*)d_ws + 768 + 73728;

    k_prep<<<288, 256, 0, stream>>>(cw, b1, pa, b2, sf, theta, wfr);
    k1_signs_shortcut<<<NB * HP, 256, 0, stream>>>(x, theta, pw, SB, out);
    k2_conv<<<1024, 256, 0, stream>>>(SB, wfr, sf, out);
}